// Round 6
// baseline (865.548 us; speedup 1.0000x reference)
//
#include <hip/hip_runtime.h>

#define N_NODES 100000
#define N_EDGES 1600000
#define NBUCK 196          // 512 nodes per bucket (dst >> 9)
#define BCAP 9600          // expected 8192 +- 91; >15 sigma headroom
#define CH 4096            // edges per multisplit chunk
#define NCHUNK ((N_EDGES + CH - 1) / CH)  // 391
#define DBINS 64           // degree bins for the node sort (deg>=63 -> bin 63)

typedef __attribute__((ext_vector_type(2))) _Float16 half2v;
typedef __attribute__((ext_vector_type(4))) _Float16 half4v;
typedef __attribute__((ext_vector_type(8))) _Float16 half8v;
typedef __attribute__((ext_vector_type(4))) float f32x4;

__device__ __forceinline__ float4 loadX4(const float* X, size_t idx) {
    return *(const float4*)(X + idx);
}
__device__ __forceinline__ float4 loadX4(const _Float16* X, size_t idx) {
    half4v h = *(const half4v*)(X + idx);
    return make_float4((float)h.x, (float)h.y, (float)h.z, (float)h.w);
}

// ---------------- counting-sort CSR build (R1 structure, known-good) ----------------

__global__ __launch_bounds__(256) void zero_small(int* p, int n) {
    int i = blockIdx.x * blockDim.x + threadIdx.x;
    if (i < n) p[i] = 0;
}

__global__ __launch_bounds__(256) void multisplit(const int* __restrict__ src,
                                                  const int* __restrict__ dst,
                                                  int* cursor,
                                                  int* __restrict__ bucketed, int e) {
    __shared__ int cnt[NBUCK];
    __shared__ int basel[NBUCK];
    const int t = threadIdx.x;
    const int base_e = blockIdx.x * CH;

    int myS[16], myD[16];
    for (int i = t; i < NBUCK; i += 256) cnt[i] = 0;
    __syncthreads();

#pragma unroll
    for (int k = 0; k < 16; ++k) {
        int i = base_e + k * 256 + t;
        if (i < e) {
            myS[k] = src[i];
            myD[k] = dst[i];
            atomicAdd(&cnt[myD[k] >> 9], 1);
        } else {
            myD[k] = -1;
        }
    }
    __syncthreads();
    for (int i = t; i < NBUCK; i += 256) basel[i] = atomicAdd(&cursor[i], cnt[i]);
    __syncthreads();
    for (int i = t; i < NBUCK; i += 256) cnt[i] = 0;
    __syncthreads();

#pragma unroll
    for (int k = 0; k < 16; ++k) {
        if (myD[k] >= 0) {
            int b = myD[k] >> 9;
            int pos = basel[b] + atomicAdd(&cnt[b], 1);
            if (pos < BCAP)
                bucketed[(size_t)b * BCAP + pos] = ((myD[k] & 511) << 17) | myS[k];
        }
    }
}

__global__ __launch_bounds__(256) void bucket_scan(const int* __restrict__ cursor,
                                                   int* __restrict__ gbase) {
    __shared__ int sm[256];
    const int t = threadIdx.x;
    int v = (t < NBUCK) ? cursor[t] : 0;
    sm[t] = v;
    __syncthreads();
    for (int off = 1; off < 256; off <<= 1) {
        int u = (t >= off) ? sm[t - off] : 0;
        __syncthreads();
        sm[t] += u;
        __syncthreads();
    }
    if (t < NBUCK) gbase[t] = sm[t] - v;
    if (t == NBUCK - 1) gbase[NBUCK] = sm[t];
}

__global__ __launch_bounds__(512) void build_csr(const int* __restrict__ bucketed,
                                                 const int* __restrict__ gbase,
                                                 int* __restrict__ row_ptr,
                                                 float* __restrict__ dinv,
                                                 int* __restrict__ csr_src, int n) {
    __shared__ int vals[BCAP];
    __shared__ int cnt[512];
    __shared__ int lcur[512];
    const int b = blockIdx.x;
    const int t = threadIdx.x;
    const int nb0 = b * 512;
    const int nn = min(512, n - nb0);
    const int gb = gbase[b];
    const int m = gbase[b + 1] - gb;

    cnt[t] = 0;
    __syncthreads();
    for (int i = t; i < m; i += 512) {
        int v = bucketed[(size_t)b * BCAP + i];
        vals[i] = v;
        atomicAdd(&cnt[v >> 17], 1);
    }
    __syncthreads();

    int deg = cnt[t];
    for (int off = 1; off < 512; off <<= 1) {
        int u = (t >= off) ? cnt[t - off] : 0;
        __syncthreads();
        cnt[t] += u;
        __syncthreads();
    }
    int offv = cnt[t] - deg;
    __syncthreads();
    cnt[t] = offv;
    lcur[t] = 0;
    if (t < nn) {
        row_ptr[nb0 + t] = gb + offv;
        dinv[nb0 + t] = rsqrtf((float)(deg + 1));
    }
    if (b == NBUCK - 1 && t == 0) row_ptr[n] = gb + m;
    __syncthreads();

    for (int i = t; i < m; i += 512) {
        int v = vals[i];
        int node = v >> 17;
        int pos = atomicAdd(&lcur[node], 1);
        csr_src[gb + cnt[node] + pos] = v & 0x1FFFF;
    }
}

// ---------------- degree-sort: perm[] = nodes ordered by degree ----------------
// Equalizes degree within each wave's groups so the wave-max loop has ~zero
// padding -> minimizes divergent-gather instruction count (the measured cost).

__global__ __launch_bounds__(256) void deg_hist(const int* __restrict__ row_ptr,
                                                int* __restrict__ hist, int n) {
    int i = blockIdx.x * 256 + threadIdx.x;
    if (i < n) {
        int deg = row_ptr[i + 1] - row_ptr[i];
        atomicAdd(&hist[min(deg, DBINS - 1)], 1);
    }
}

__global__ __launch_bounds__(64) void hist_scan(const int* __restrict__ hist,
                                                int* __restrict__ base) {
    __shared__ int sm[DBINS];
    const int t = threadIdx.x;
    int v = hist[t];
    sm[t] = v;
    __syncthreads();
    for (int off = 1; off < DBINS; off <<= 1) {
        int u = (t >= off) ? sm[t - off] : 0;
        __syncthreads();
        sm[t] += u;
        __syncthreads();
    }
    base[t] = sm[t] - v;
}

__global__ __launch_bounds__(256) void perm_scatter(const int* __restrict__ row_ptr,
                                                    const int* __restrict__ base,
                                                    int* cursor,
                                                    int* __restrict__ perm, int n) {
    int i = blockIdx.x * 256 + threadIdx.x;
    if (i < n) {
        int deg = row_ptr[i + 1] - row_ptr[i];
        int b = min(deg, DBINS - 1);
        int pos = base[b] + atomicAdd(&cursor[b], 1);
        perm[pos] = i;
    }
}

// ---------------- W pre-transpose: Wt[n][k] = fp16(W[k][n]) ----------------

template <int K>
__global__ __launch_bounds__(256) void transpose_w(const float* __restrict__ W,
                                                   _Float16* __restrict__ Wt) {
    int i = blockIdx.x * 256 + threadIdx.x;
    if (i < K * 64) {
        int k = i >> 6, nn = i & 63;
        Wt[(size_t)nn * K + k] = (_Float16)W[i];
    }
}

// ---------------- MFMA GEMM: Y[N,64] = fp16(dinv * X[N,K] @ W) ----------------
// Also zeroes row n of Y (aggregation zero-row target).

__device__ __forceinline__ void stageX_rows(const float* X, _Float16* Xl, int t,
                                            int row0, int n, int K, int SP) {
    for (int i = t; i < 64 * K / 4; i += 256) {
        int r = i / (K / 4), c = (i % (K / 4)) * 4;
        int grow = min(row0 + r, n - 1);
        float4 v = *(const float4*)(X + (size_t)grow * K + c);
        half4v h = {(_Float16)v.x, (_Float16)v.y, (_Float16)v.z, (_Float16)v.w};
        *(half4v*)(Xl + r * SP + c) = h;
    }
}
__device__ __forceinline__ void stageX_rows(const _Float16* X, _Float16* Xl, int t,
                                            int row0, int n, int K, int SP) {
    for (int i = t; i < 64 * K / 8; i += 256) {
        int r = i / (K / 8), c = (i % (K / 8)) * 8;
        int grow = min(row0 + r, n - 1);
        *(half8v*)(Xl + r * SP + c) = *(const half8v*)(X + (size_t)grow * K + c);
    }
}

template <int K, typename XT>
__global__ __launch_bounds__(256) void gemm_mfma64(const XT* __restrict__ X,
                                                   const _Float16* __restrict__ Wt,
                                                   const float* __restrict__ dinv,
                                                   _Float16* __restrict__ Y, int n) {
    constexpr int SP = K + 8;
    __shared__ _Float16 Xl[64 * SP];
    __shared__ _Float16 Wl[64 * SP];
    const int t = threadIdx.x;
    const int wave = t >> 6, lane = t & 63;
    const int row0 = blockIdx.x * 64;
    const int m = lane & 15, quad = lane >> 4;

    // zero row n of Y (aggregation zero-row target)
    if (blockIdx.x == 0 && t < 32) ((int*)(Y + (size_t)n * 64))[t] = 0;

    // stage Wt (straight padded copy) and X rows
    for (int i = t; i < 64 * K / 8; i += 256) {
        int r = i / (K / 8), c = (i % (K / 8)) * 8;
        *(half8v*)(Wl + r * SP + c) = *(const half8v*)(Wt + (size_t)r * K + c);
    }
    stageX_rows(X, Xl, t, row0, n, K, SP);
    __syncthreads();

    f32x4 acc[4] = {{0,0,0,0},{0,0,0,0},{0,0,0,0},{0,0,0,0}};
#pragma unroll
    for (int k0 = 0; k0 < K; k0 += 32) {
        half8v a = *(const half8v*)(Xl + (wave * 16 + m) * SP + k0 + quad * 8);
#pragma unroll
        for (int ct = 0; ct < 4; ++ct) {
            half8v b = *(const half8v*)(Wl + (ct * 16 + m) * SP + k0 + quad * 8);
            acc[ct] = __builtin_amdgcn_mfma_f32_16x16x32_f16(a, b, acc[ct], 0, 0, 0);
        }
    }

    // D: col = lane&15 (=m), row = quad*4 + reg
    float dv[4];
#pragma unroll
    for (int r = 0; r < 4; ++r) {
        int row = row0 + wave * 16 + quad * 4 + r;
        dv[r] = dinv[min(row, n - 1)];
    }
#pragma unroll
    for (int ct = 0; ct < 4; ++ct) {
#pragma unroll
        for (int r = 0; r < 4; ++r) {
            int row = row0 + wave * 16 + quad * 4 + r;
            if (row < n)
                Y[(size_t)row * 64 + ct * 16 + m] = (_Float16)(dv[r] * acc[ct][r]);
        }
    }
}

// ---------------- VALU GEMM (layer 3, COUT=40): Y = fp16(dinv * X @ W) ----------------

template <int K, int COUT, typename XT>
__global__ __launch_bounds__(256) void gemm_rt(const XT* __restrict__ X,
                                               const float* __restrict__ W,
                                               const float* __restrict__ dinv,
                                               _Float16* __restrict__ Y, int n) {
    constexpr int KC = 64;
    constexpr int S = KC + 4;
    constexpr int NCH = K / KC;
    __shared__ float Xl[64 * S];
    __shared__ float Wl[KC * COUT];

    const int t = threadIdx.x;
    const int row0 = blockIdx.x * 64;
    const int cg = (t & 15) * 4;
    const int rg = (t >> 4) * 4;

    // zero row n of Y (aggregation zero-row target): COUT halves = COUT/2 ints
    if (blockIdx.x == 0 && t < COUT / 2) ((int*)(Y + (size_t)n * COUT))[t] = 0;

    float acc[4][4] = {};

#pragma unroll
    for (int ch = 0; ch < NCH; ++ch) {
        const int k0 = ch * KC;
        for (int i = t; i < 64 * KC / 4; i += 256) {
            int r = i >> 4;
            int k = (i & 15) * 4;
            int grow = min(row0 + r, n - 1);
            *(float4*)(Xl + r * S + k) = loadX4(X, (size_t)grow * K + k0 + k);
        }
        for (int i = t; i < KC * COUT / 4; i += 256) {
            *(float4*)(Wl + i * 4) = *(const float4*)(W + (size_t)k0 * COUT + (size_t)i * 4);
        }
        __syncthreads();

        if (cg < COUT) {
#pragma unroll 4
            for (int k = 0; k < KC; ++k) {
                float4 w = *(const float4*)(Wl + k * COUT + cg);
                float x0 = Xl[(rg + 0) * S + k];
                float x1 = Xl[(rg + 1) * S + k];
                float x2 = Xl[(rg + 2) * S + k];
                float x3 = Xl[(rg + 3) * S + k];
                acc[0][0] += x0 * w.x; acc[0][1] += x0 * w.y; acc[0][2] += x0 * w.z; acc[0][3] += x0 * w.w;
                acc[1][0] += x1 * w.x; acc[1][1] += x1 * w.y; acc[1][2] += x1 * w.z; acc[1][3] += x1 * w.w;
                acc[2][0] += x2 * w.x; acc[2][1] += x2 * w.y; acc[2][2] += x2 * w.z; acc[2][3] += x2 * w.w;
                acc[3][0] += x3 * w.x; acc[3][1] += x3 * w.y; acc[3][2] += x3 * w.z; acc[3][3] += x3 * w.w;
            }
        }
        __syncthreads();
    }

    if (cg < COUT) {
#pragma unroll
        for (int r = 0; r < 4; ++r) {
            int row = row0 + rg + r;
            if (row < n) {
                float d = dinv[row];
                half4v o = { (_Float16)(d * acc[r][0]), (_Float16)(d * acc[r][1]),
                             (_Float16)(d * acc[r][2]), (_Float16)(d * acc[r][3]) };
                *(half4v*)(Y + (size_t)row * COUT + cg) = o;
            }
        }
    }
}

// ---------------- aggregation, COUT=64: node per 8-lane group, DEGREE-SORTED ----------------
// Same body as R1's aggregate64c, but nodes are visited in degree-sorted order
// (node = perm[gi]) so all 8 groups of a wave have ~equal degree and the
// wave-max loop executes ~ceil(deg/8) gather instructions with near-zero padding.

template <bool RELU>
__global__ __launch_bounds__(256) void aggregate64g(const _Float16* __restrict__ tS,
                                                    const int* __restrict__ row_ptr,
                                                    const int* __restrict__ csr_src,
                                                    const int* __restrict__ perm,
                                                    const float* __restrict__ dinv,
                                                    const float* __restrict__ bias,
                                                    _Float16* __restrict__ out, int n) {
    const int t = threadIdx.x;
    const int lane = t & 63;
    const int c8 = lane & 7;
    const int node = perm[blockIdx.x * 32 + (t >> 3)];   // N % 32 == 0
    const half8v* tS8 = (const half8v*)tS;
    const int bpb = (lane & 56) << 2;              // group base lane * 4 (bperm byte addr)

    const int beg = row_ptr[node];
    const int cnt = row_ptr[node + 1] - beg;
    const int cl = (cnt > 0) ? cnt - 1 : 0;

    // wave-wide max degree (~= own degree after sort)
    int mc = cnt;
    mc = max(mc, __shfl_xor(mc, 8));
    mc = max(mc, __shfl_xor(mc, 16));
    mc = max(mc, __shfl_xor(mc, 32));

    half8v acc0, acc1;
#pragma unroll
    for (int i = 0; i < 8; ++i) { acc0[i] = (_Float16)0; acc1[i] = (_Float16)0; }

    for (int j0 = 0; j0 < mc; j0 += 8) {
        int sj = csr_src[beg + min(j0 + c8, cl)];
#pragma unroll
        for (int jj = 0; jj < 8; ++jj) {
            int e = __builtin_amdgcn_ds_bpermute(bpb + jj * 4, sj);
            e = (j0 + jj < cnt) ? e : n;           // invalid -> zero row
            half8v v = tS8[(size_t)e * 8 + c8];
            if (jj & 1) acc1 += v; else acc0 += v;
        }
    }

    // promote to fp32, add self + bias, scale by dinv[node]
    float acc[8];
#pragma unroll
    for (int i = 0; i < 8; ++i) acc[i] = (float)acc0[i] + (float)acc1[i];

    half8v selfh = tS8[(size_t)node * 8 + c8];
    float4 b0 = ((const float4*)bias)[c8 * 2];
    float4 b1 = ((const float4*)bias)[c8 * 2 + 1];
    const float bb[8] = {b0.x, b0.y, b0.z, b0.w, b1.x, b1.y, b1.z, b1.w};
    float d = dinv[node];
    half8v o;
#pragma unroll
    for (int i = 0; i < 8; ++i) {
        float v = bb[i] + d * (acc[i] + (float)selfh[i]);
        if (RELU) v = fmaxf(v, 0.0f);
        o[i] = (_Float16)v;
    }
    ((half8v*)out)[(size_t)node * 8 + c8] = o;
}

// ---------------- aggregation, COUT=40: node per 5-lane group, DEGREE-SORTED ----------------
// 80B row = 5 lanes x dwordx4 (80 % 16 == 0 so rows are 16B-aligned).
// 12 groups/wave (lanes 60-63 idle), 48 nodes/block, 12 edges per gather
// instruction and only 5 addresses per edge (vs 10 in the 10-lane layout).

__global__ __launch_bounds__(256) void aggregate40p(const _Float16* __restrict__ tS,
                                                    const int* __restrict__ row_ptr,
                                                    const int* __restrict__ csr_src,
                                                    const int* __restrict__ perm,
                                                    const float* __restrict__ dinv,
                                                    const float* __restrict__ bias,
                                                    float* __restrict__ out, int n) {
    const int t = threadIdx.x;
    const int lane = t & 63;
    const int wave = t >> 6;
    const int g = lane / 5;                        // 0..12 (g==12 -> lanes 60-63 idle)
    const int c5 = lane - g * 5;
    const int gi = blockIdx.x * 48 + wave * 12 + g;
    const bool act = (g < 12) && (gi < n);
    const int node = act ? perm[gi] : 0;
    const half8v* tS8r = (const half8v*)tS;        // row stride 5 half8v = 80B
    const int bpb = g * 20;                        // group base lane * 4

    const int beg = act ? row_ptr[node] : 0;
    const int cnt = act ? (row_ptr[node + 1] - beg) : 0;
    const int cl = (cnt > 0) ? cnt - 1 : 0;

    int mc = cnt;
    mc = max(mc, __shfl_xor(mc, 1));
    mc = max(mc, __shfl_xor(mc, 2));
    mc = max(mc, __shfl_xor(mc, 4));
    mc = max(mc, __shfl_xor(mc, 8));
    mc = max(mc, __shfl_xor(mc, 16));
    mc = max(mc, __shfl_xor(mc, 32));

    half8v a0, a1;
#pragma unroll
    for (int i = 0; i < 8; ++i) { a0[i] = (_Float16)0; a1[i] = (_Float16)0; }

    for (int j0 = 0; j0 < mc; j0 += 5) {
        int sj = csr_src[beg + min(j0 + c5, cl)];
#pragma unroll
        for (int jj = 0; jj < 5; ++jj) {
            int e = __builtin_amdgcn_ds_bpermute(bpb + jj * 4, sj);
            e = (j0 + jj < cnt) ? e : n;           // invalid -> zero row
            half8v v = tS8r[(size_t)e * 5 + c5];
            if (jj & 1) a1 += v; else a0 += v;
        }
    }

    if (act) {
        float acc[8];
#pragma unroll
        for (int i = 0; i < 8; ++i) acc[i] = (float)a0[i] + (float)a1[i];

        half8v selfh = tS8r[(size_t)node * 5 + c5];
        float4 b0 = ((const float4*)bias)[c5 * 2];
        float4 b1 = ((const float4*)bias)[c5 * 2 + 1];
        float d = dinv[node];
        float4 o0, o1;
        o0.x = b0.x + d * (acc[0] + (float)selfh[0]);
        o0.y = b0.y + d * (acc[1] + (float)selfh[1]);
        o0.z = b0.z + d * (acc[2] + (float)selfh[2]);
        o0.w = b0.w + d * (acc[3] + (float)selfh[3]);
        o1.x = b1.x + d * (acc[4] + (float)selfh[4]);
        o1.y = b1.y + d * (acc[5] + (float)selfh[5]);
        o1.z = b1.z + d * (acc[6] + (float)selfh[6]);
        o1.w = b1.w + d * (acc[7] + (float)selfh[7]);
        *(float4*)(out + (size_t)node * 40 + c5 * 8) = o0;
        *(float4*)(out + (size_t)node * 40 + c5 * 8 + 4) = o1;
    }
}

// ---------------- launch ----------------

extern "C" void kernel_launch(void* const* d_in, const int* in_sizes, int n_in,
                              void* d_out, int out_size, void* d_ws, size_t ws_size,
                              hipStream_t stream) {
    const float* x  = (const float*)d_in[0];
    const int*   ei = (const int*)d_in[1];
    const int*   src = ei;
    const int*   dst = ei + N_EDGES;
    const float* W1 = (const float*)d_in[2];
    const float* b1 = (const float*)d_in[3];
    const float* W2 = (const float*)d_in[4];
    const float* b2 = (const float*)d_in[5];
    const float* W3 = (const float*)d_in[6];
    const float* b3 = (const float*)d_in[7];
    float* out = (float*)d_out;

    const int N = N_NODES, E = N_EDGES;

    char* p = (char*)d_ws;
    int*   cursor   = (int*)p;              p += 256 * 4;
    int*   gbase    = (int*)p;              p += 256 * 4;
    int*   histx    = (int*)p;              p += 256 * 4;   // hist[64] + cursor2[64] + base[64]
    float* dinv     = (float*)p;            p += (size_t)N * 4;
    int*   row_ptr  = (int*)p;              p += (size_t)(N + 4) * 4;
    int*   perm     = (int*)p;              p += (size_t)N * 4;
    int*   bucketed = (int*)p;              p += (size_t)NBUCK * BCAP * 4;
    int*   csr_src  = (int*)p;              p += (size_t)(E + 64) * 4;   // +64 slack for clamped reads
    p = (char*)(((size_t)p + 15) & ~(size_t)15);
    _Float16* Wt1   = (_Float16*)p;         p += (size_t)64 * 128 * 2;
    _Float16* Wt2   = (_Float16*)p;         p += (size_t)64 * 64 * 2;
    _Float16* bufA  = (_Float16*)p;         p += (size_t)(N + 64) * 64 * 2;  // fp16 tS (+zero row)
    p = (char*)(((size_t)p + 15) & ~(size_t)15);
    _Float16* bufB  = (_Float16*)p;         p += (size_t)N * 64 * 2;  // fp16 h

    int* hist    = histx;
    int* cursor2 = histx + 64;
    int* dbase   = histx + 128;

    // ---- counting-sort CSR build + W pre-transpose ----
    zero_small<<<1, 256, 0, stream>>>(cursor, NBUCK);
    zero_small<<<1, 256, 0, stream>>>(histx, 128);   // hist + cursor2
    transpose_w<128><<<32, 256, 0, stream>>>(W1, Wt1);
    transpose_w<64><<<16, 256, 0, stream>>>(W2, Wt2);
    multisplit<<<NCHUNK, 256, 0, stream>>>(src, dst, cursor, bucketed, E);
    bucket_scan<<<1, 256, 0, stream>>>(cursor, gbase);
    build_csr<<<NBUCK, 512, 0, stream>>>(bucketed, gbase, row_ptr, dinv, csr_src, N);

    // ---- degree sort: perm = nodes ordered by degree ----
    const int nThreadGrid = (N + 255) / 256;
    deg_hist<<<nThreadGrid, 256, 0, stream>>>(row_ptr, hist, N);
    hist_scan<<<1, 64, 0, stream>>>(hist, dbase);
    perm_scatter<<<nThreadGrid, 256, 0, stream>>>(row_ptr, dbase, cursor2, perm, N);

    const int agg64Grid = N / 32;            // 3125, exact
    const int agg40Grid = (N + 47) / 48;     // 2084
    const int gemmGrid = (N + 63) / 64;

    // layer 1: x fp32 -> tS fp16 (MFMA); aggregate+relu -> h fp16
    gemm_mfma64<128, float><<<gemmGrid, 256, 0, stream>>>(x, Wt1, dinv, bufA, N);
    aggregate64g<true><<<agg64Grid, 256, 0, stream>>>(bufA, row_ptr, csr_src, perm, dinv, b1, bufB, N);

    // layer 2: h fp16 -> tS fp16 (MFMA); aggregate+relu -> h fp16
    gemm_mfma64<64, _Float16><<<gemmGrid, 256, 0, stream>>>(bufB, Wt2, dinv, bufA, N);
    aggregate64g<true><<<agg64Grid, 256, 0, stream>>>(bufA, row_ptr, csr_src, perm, dinv, b2, bufB, N);

    // layer 3: h fp16 -> tS40 fp16 (VALU); aggregate -> out fp32
    gemm_rt<64, 40, _Float16><<<gemmGrid, 256, 0, stream>>>(bufB, W3, dinv, bufA, N);
    aggregate40p<<<agg40Grid, 256, 0, stream>>>(bufA, row_ptr, csr_src, perm, dinv, b3, out, N);
}

// Round 7
// 345.212 us; speedup vs baseline: 2.5073x; 2.5073x over previous
//
#include <hip/hip_runtime.h>

#define N_NODES 100000
#define N_EDGES 1600000
#define NBUCK 196          // 512 nodes per bucket (dst >> 9)
#define BCAP 9600          // expected 8192 +- 91; >15 sigma headroom
#define CH 4096            // edges per multisplit chunk
#define NCHUNK ((N_EDGES + CH - 1) / CH)  // 391
#define DBINS 64           // degree bins for the node sort (deg>=63 -> bin 63)

typedef __attribute__((ext_vector_type(2))) _Float16 half2v;
typedef __attribute__((ext_vector_type(4))) _Float16 half4v;
typedef __attribute__((ext_vector_type(8))) _Float16 half8v;
typedef __attribute__((ext_vector_type(4))) float f32x4;

__device__ __forceinline__ float4 loadX4(const float* X, size_t idx) {
    return *(const float4*)(X + idx);
}
__device__ __forceinline__ float4 loadX4(const _Float16* X, size_t idx) {
    half4v h = *(const half4v*)(X + idx);
    return make_float4((float)h.x, (float)h.y, (float)h.z, (float)h.w);
}

// ---------------- counting-sort CSR build ----------------

__global__ __launch_bounds__(256) void zero_small(int* p, int n) {
    int i = blockIdx.x * blockDim.x + threadIdx.x;
    if (i < n) p[i] = 0;
}

__global__ __launch_bounds__(256) void multisplit(const int* __restrict__ src,
                                                  const int* __restrict__ dst,
                                                  int* cursor,
                                                  int* __restrict__ bucketed, int e) {
    __shared__ int cnt[NBUCK];
    __shared__ int basel[NBUCK];
    const int t = threadIdx.x;
    const int base_e = blockIdx.x * CH;

    int myS[16], myD[16];
    for (int i = t; i < NBUCK; i += 256) cnt[i] = 0;
    __syncthreads();

#pragma unroll
    for (int k = 0; k < 16; ++k) {
        int i = base_e + k * 256 + t;
        if (i < e) {
            myS[k] = src[i];
            myD[k] = dst[i];
            atomicAdd(&cnt[myD[k] >> 9], 1);
        } else {
            myD[k] = -1;
        }
    }
    __syncthreads();
    for (int i = t; i < NBUCK; i += 256) basel[i] = atomicAdd(&cursor[i], cnt[i]);
    __syncthreads();
    for (int i = t; i < NBUCK; i += 256) cnt[i] = 0;
    __syncthreads();

#pragma unroll
    for (int k = 0; k < 16; ++k) {
        if (myD[k] >= 0) {
            int b = myD[k] >> 9;
            int pos = basel[b] + atomicAdd(&cnt[b], 1);
            if (pos < BCAP)
                bucketed[(size_t)b * BCAP + pos] = ((myD[k] & 511) << 17) | myS[k];
        }
    }
}

__global__ __launch_bounds__(256) void bucket_scan(const int* __restrict__ cursor,
                                                   int* __restrict__ gbase) {
    __shared__ int sm[256];
    const int t = threadIdx.x;
    int v = (t < NBUCK) ? cursor[t] : 0;
    sm[t] = v;
    __syncthreads();
    for (int off = 1; off < 256; off <<= 1) {
        int u = (t >= off) ? sm[t - off] : 0;
        __syncthreads();
        sm[t] += u;
        __syncthreads();
    }
    if (t < NBUCK) gbase[t] = sm[t] - v;
    if (t == NBUCK - 1) gbase[NBUCK] = sm[t];
}

// build_csr also accumulates the degree histogram (LDS-privatized; one global
// atomicAdd per block per bin) so no separate deg_hist pass over row_ptr.
__global__ __launch_bounds__(512) void build_csr(const int* __restrict__ bucketed,
                                                 const int* __restrict__ gbase,
                                                 int* __restrict__ row_ptr,
                                                 float* __restrict__ dinv,
                                                 int* __restrict__ csr_src,
                                                 int* __restrict__ hist, int n) {
    __shared__ int vals[BCAP];
    __shared__ int cnt[512];
    __shared__ int lcur[512];
    __shared__ int lhist[DBINS];
    const int b = blockIdx.x;
    const int t = threadIdx.x;
    const int nb0 = b * 512;
    const int nn = min(512, n - nb0);
    const int gb = gbase[b];
    const int m = gbase[b + 1] - gb;

    cnt[t] = 0;
    if (t < DBINS) lhist[t] = 0;
    __syncthreads();
    for (int i = t; i < m; i += 512) {
        int v = bucketed[(size_t)b * BCAP + i];
        vals[i] = v;
        atomicAdd(&cnt[v >> 17], 1);
    }
    __syncthreads();

    int deg = cnt[t];
    if (t < nn) atomicAdd(&lhist[min(deg, DBINS - 1)], 1);
    for (int off = 1; off < 512; off <<= 1) {
        int u = (t >= off) ? cnt[t - off] : 0;
        __syncthreads();
        cnt[t] += u;
        __syncthreads();
    }
    int offv = cnt[t] - deg;
    __syncthreads();
    cnt[t] = offv;
    lcur[t] = 0;
    if (t < nn) {
        row_ptr[nb0 + t] = gb + offv;
        dinv[nb0 + t] = rsqrtf((float)(deg + 1));
    }
    if (b == NBUCK - 1 && t == 0) row_ptr[n] = gb + m;
    __syncthreads();

    for (int i = t; i < m; i += 512) {
        int v = vals[i];
        int node = v >> 17;
        int pos = atomicAdd(&lcur[node], 1);
        csr_src[gb + cnt[node] + pos] = v & 0x1FFFF;
    }
    if (t < DBINS && lhist[t] > 0) atomicAdd(&hist[t], lhist[t]);
}

// ---------------- degree-sort: perm[] = nodes grouped by degree ----------------

__global__ __launch_bounds__(64) void hist_scan(const int* __restrict__ hist,
                                                int* __restrict__ base) {
    __shared__ int sm[DBINS];
    const int t = threadIdx.x;
    int v = hist[t];
    sm[t] = v;
    __syncthreads();
    for (int off = 1; off < DBINS; off <<= 1) {
        int u = (t >= off) ? sm[t - off] : 0;
        __syncthreads();
        sm[t] += u;
        __syncthreads();
    }
    base[t] = sm[t] - v;
}

// LDS-privatized scatter: per-block LDS counts give each thread a local rank;
// one global atomicAdd per (block,bin) reserves the block's segment. Non-stable
// across blocks (irrelevant: any grouping by degree is equivalent).
__global__ __launch_bounds__(256) void perm_scatter(const int* __restrict__ row_ptr,
                                                    const int* __restrict__ base,
                                                    int* gcursor,
                                                    int* __restrict__ perm, int n) {
    __shared__ int lcnt[DBINS];
    __shared__ int lbase[DBINS];
    const int t = threadIdx.x;
    if (t < DBINS) lcnt[t] = 0;
    __syncthreads();
    const int i = blockIdx.x * 256 + t;
    int bin = 0, lpos = 0;
    if (i < n) {
        int deg = row_ptr[i + 1] - row_ptr[i];
        bin = min(deg, DBINS - 1);
        lpos = atomicAdd(&lcnt[bin], 1);
    }
    __syncthreads();
    if (t < DBINS && lcnt[t] > 0) lbase[t] = atomicAdd(&gcursor[t], lcnt[t]);
    __syncthreads();
    if (i < n) perm[base[bin] + lbase[bin] + lpos] = i;
}

// ---------------- W pre-transpose: Wt[n][k] = fp16(W[k][n]) ----------------

template <int K>
__global__ __launch_bounds__(256) void transpose_w(const float* __restrict__ W,
                                                   _Float16* __restrict__ Wt) {
    int i = blockIdx.x * 256 + threadIdx.x;
    if (i < K * 64) {
        int k = i >> 6, nn = i & 63;
        Wt[(size_t)nn * K + k] = (_Float16)W[i];
    }
}

// ---------------- MFMA GEMM: Y[N,64] = fp16(dinv * X[N,K] @ W) ----------------
// Also zeroes row n of Y (aggregation zero-row target).

__device__ __forceinline__ void stageX_rows(const float* X, _Float16* Xl, int t,
                                            int row0, int n, int K, int SP) {
    for (int i = t; i < 64 * K / 4; i += 256) {
        int r = i / (K / 4), c = (i % (K / 4)) * 4;
        int grow = min(row0 + r, n - 1);
        float4 v = *(const float4*)(X + (size_t)grow * K + c);
        half4v h = {(_Float16)v.x, (_Float16)v.y, (_Float16)v.z, (_Float16)v.w};
        *(half4v*)(Xl + r * SP + c) = h;
    }
}
__device__ __forceinline__ void stageX_rows(const _Float16* X, _Float16* Xl, int t,
                                            int row0, int n, int K, int SP) {
    for (int i = t; i < 64 * K / 8; i += 256) {
        int r = i / (K / 8), c = (i % (K / 8)) * 8;
        int grow = min(row0 + r, n - 1);
        *(half8v*)(Xl + r * SP + c) = *(const half8v*)(X + (size_t)grow * K + c);
    }
}

template <int K, typename XT>
__global__ __launch_bounds__(256) void gemm_mfma64(const XT* __restrict__ X,
                                                   const _Float16* __restrict__ Wt,
                                                   const float* __restrict__ dinv,
                                                   _Float16* __restrict__ Y, int n) {
    constexpr int SP = K + 8;
    __shared__ _Float16 Xl[64 * SP];
    __shared__ _Float16 Wl[64 * SP];
    const int t = threadIdx.x;
    const int wave = t >> 6, lane = t & 63;
    const int row0 = blockIdx.x * 64;
    const int m = lane & 15, quad = lane >> 4;

    // zero row n of Y (aggregation zero-row target)
    if (blockIdx.x == 0 && t < 32) ((int*)(Y + (size_t)n * 64))[t] = 0;

    // stage Wt (straight padded copy) and X rows
    for (int i = t; i < 64 * K / 8; i += 256) {
        int r = i / (K / 8), c = (i % (K / 8)) * 8;
        *(half8v*)(Wl + r * SP + c) = *(const half8v*)(Wt + (size_t)r * K + c);
    }
    stageX_rows(X, Xl, t, row0, n, K, SP);
    __syncthreads();

    f32x4 acc[4] = {{0,0,0,0},{0,0,0,0},{0,0,0,0},{0,0,0,0}};
#pragma unroll
    for (int k0 = 0; k0 < K; k0 += 32) {
        half8v a = *(const half8v*)(Xl + (wave * 16 + m) * SP + k0 + quad * 8);
#pragma unroll
        for (int ct = 0; ct < 4; ++ct) {
            half8v b = *(const half8v*)(Wl + (ct * 16 + m) * SP + k0 + quad * 8);
            acc[ct] = __builtin_amdgcn_mfma_f32_16x16x32_f16(a, b, acc[ct], 0, 0, 0);
        }
    }

    // D: col = lane&15 (=m), row = quad*4 + reg
    float dv[4];
#pragma unroll
    for (int r = 0; r < 4; ++r) {
        int row = row0 + wave * 16 + quad * 4 + r;
        dv[r] = dinv[min(row, n - 1)];
    }
#pragma unroll
    for (int ct = 0; ct < 4; ++ct) {
#pragma unroll
        for (int r = 0; r < 4; ++r) {
            int row = row0 + wave * 16 + quad * 4 + r;
            if (row < n)
                Y[(size_t)row * 64 + ct * 16 + m] = (_Float16)(dv[r] * acc[ct][r]);
        }
    }
}

// ---------------- VALU GEMM (layer 3, COUT=40): Y = fp16(dinv * X @ W) ----------------

template <int K, int COUT, typename XT>
__global__ __launch_bounds__(256) void gemm_rt(const XT* __restrict__ X,
                                               const float* __restrict__ W,
                                               const float* __restrict__ dinv,
                                               _Float16* __restrict__ Y, int n) {
    constexpr int KC = 64;
    constexpr int S = KC + 4;
    constexpr int NCH = K / KC;
    __shared__ float Xl[64 * S];
    __shared__ float Wl[KC * COUT];

    const int t = threadIdx.x;
    const int row0 = blockIdx.x * 64;
    const int cg = (t & 15) * 4;
    const int rg = (t >> 4) * 4;

    // zero row n of Y (aggregation zero-row target): COUT halves = COUT/2 ints
    if (blockIdx.x == 0 && t < COUT / 2) ((int*)(Y + (size_t)n * COUT))[t] = 0;

    float acc[4][4] = {};

#pragma unroll
    for (int ch = 0; ch < NCH; ++ch) {
        const int k0 = ch * KC;
        for (int i = t; i < 64 * KC / 4; i += 256) {
            int r = i >> 4;
            int k = (i & 15) * 4;
            int grow = min(row0 + r, n - 1);
            *(float4*)(Xl + r * S + k) = loadX4(X, (size_t)grow * K + k0 + k);
        }
        for (int i = t; i < KC * COUT / 4; i += 256) {
            *(float4*)(Wl + i * 4) = *(const float4*)(W + (size_t)k0 * COUT + (size_t)i * 4);
        }
        __syncthreads();

        if (cg < COUT) {
#pragma unroll 4
            for (int k = 0; k < KC; ++k) {
                float4 w = *(const float4*)(Wl + k * COUT + cg);
                float x0 = Xl[(rg + 0) * S + k];
                float x1 = Xl[(rg + 1) * S + k];
                float x2 = Xl[(rg + 2) * S + k];
                float x3 = Xl[(rg + 3) * S + k];
                acc[0][0] += x0 * w.x; acc[0][1] += x0 * w.y; acc[0][2] += x0 * w.z; acc[0][3] += x0 * w.w;
                acc[1][0] += x1 * w.x; acc[1][1] += x1 * w.y; acc[1][2] += x1 * w.z; acc[1][3] += x1 * w.w;
                acc[2][0] += x2 * w.x; acc[2][1] += x2 * w.y; acc[2][2] += x2 * w.z; acc[2][3] += x2 * w.w;
                acc[3][0] += x3 * w.x; acc[3][1] += x3 * w.y; acc[3][2] += x3 * w.z; acc[3][3] += x3 * w.w;
            }
        }
        __syncthreads();
    }

    if (cg < COUT) {
#pragma unroll
        for (int r = 0; r < 4; ++r) {
            int row = row0 + rg + r;
            if (row < n) {
                float d = dinv[row];
                half4v o = { (_Float16)(d * acc[r][0]), (_Float16)(d * acc[r][1]),
                             (_Float16)(d * acc[r][2]), (_Float16)(d * acc[r][3]) };
                *(half4v*)(Y + (size_t)row * COUT + cg) = o;
            }
        }
    }
}

// ---------------- aggregation, COUT=64: node per 8-lane group, DEGREE-SORTED ----------------

template <bool RELU>
__global__ __launch_bounds__(256) void aggregate64g(const _Float16* __restrict__ tS,
                                                    const int* __restrict__ row_ptr,
                                                    const int* __restrict__ csr_src,
                                                    const int* __restrict__ perm,
                                                    const float* __restrict__ dinv,
                                                    const float* __restrict__ bias,
                                                    _Float16* __restrict__ out, int n) {
    const int t = threadIdx.x;
    const int lane = t & 63;
    const int c8 = lane & 7;
    const int node = perm[blockIdx.x * 32 + (t >> 3)];   // N % 32 == 0
    const half8v* tS8 = (const half8v*)tS;
    const int bpb = (lane & 56) << 2;              // group base lane * 4 (bperm byte addr)

    const int beg = row_ptr[node];
    const int cnt = row_ptr[node + 1] - beg;
    const int cl = (cnt > 0) ? cnt - 1 : 0;

    // wave-wide max degree (~= own degree after sort)
    int mc = cnt;
    mc = max(mc, __shfl_xor(mc, 8));
    mc = max(mc, __shfl_xor(mc, 16));
    mc = max(mc, __shfl_xor(mc, 32));

    half8v acc0, acc1;
#pragma unroll
    for (int i = 0; i < 8; ++i) { acc0[i] = (_Float16)0; acc1[i] = (_Float16)0; }

    for (int j0 = 0; j0 < mc; j0 += 8) {
        int sj = csr_src[beg + min(j0 + c8, cl)];
#pragma unroll
        for (int jj = 0; jj < 8; ++jj) {
            int e = __builtin_amdgcn_ds_bpermute(bpb + jj * 4, sj);
            e = (j0 + jj < cnt) ? e : n;           // invalid -> zero row
            half8v v = tS8[(size_t)e * 8 + c8];
            if (jj & 1) acc1 += v; else acc0 += v;
        }
    }

    // promote to fp32, add self + bias, scale by dinv[node]
    float acc[8];
#pragma unroll
    for (int i = 0; i < 8; ++i) acc[i] = (float)acc0[i] + (float)acc1[i];

    half8v selfh = tS8[(size_t)node * 8 + c8];
    float4 b0 = ((const float4*)bias)[c8 * 2];
    float4 b1 = ((const float4*)bias)[c8 * 2 + 1];
    const float bb[8] = {b0.x, b0.y, b0.z, b0.w, b1.x, b1.y, b1.z, b1.w};
    float d = dinv[node];
    half8v o;
#pragma unroll
    for (int i = 0; i < 8; ++i) {
        float v = bb[i] + d * (acc[i] + (float)selfh[i]);
        if (RELU) v = fmaxf(v, 0.0f);
        o[i] = (_Float16)v;
    }
    ((half8v*)out)[(size_t)node * 8 + c8] = o;
}

// ---------------- aggregation, COUT=40: node per 5-lane group, DEGREE-SORTED ----------------
// 80B row = 5 lanes x dwordx4. 12 groups/wave (lanes 60-63 idle), 48 nodes/block.

__global__ __launch_bounds__(256) void aggregate40p(const _Float16* __restrict__ tS,
                                                    const int* __restrict__ row_ptr,
                                                    const int* __restrict__ csr_src,
                                                    const int* __restrict__ perm,
                                                    const float* __restrict__ dinv,
                                                    const float* __restrict__ bias,
                                                    float* __restrict__ out, int n) {
    const int t = threadIdx.x;
    const int lane = t & 63;
    const int wave = t >> 6;
    const int g = lane / 5;                        // 0..12 (g==12 -> lanes 60-63 idle)
    const int c5 = lane - g * 5;
    const int gi = blockIdx.x * 48 + wave * 12 + g;
    const bool act = (g < 12) && (gi < n);
    const int node = act ? perm[gi] : 0;
    const half8v* tS8r = (const half8v*)tS;        // row stride 5 half8v = 80B
    const int bpb = g * 20;                        // group base lane * 4

    const int beg = act ? row_ptr[node] : 0;
    const int cnt = act ? (row_ptr[node + 1] - beg) : 0;
    const int cl = (cnt > 0) ? cnt - 1 : 0;

    int mc = cnt;
    mc = max(mc, __shfl_xor(mc, 1));
    mc = max(mc, __shfl_xor(mc, 2));
    mc = max(mc, __shfl_xor(mc, 4));
    mc = max(mc, __shfl_xor(mc, 8));
    mc = max(mc, __shfl_xor(mc, 16));
    mc = max(mc, __shfl_xor(mc, 32));

    half8v a0, a1;
#pragma unroll
    for (int i = 0; i < 8; ++i) { a0[i] = (_Float16)0; a1[i] = (_Float16)0; }

    for (int j0 = 0; j0 < mc; j0 += 5) {
        int sj = csr_src[beg + min(j0 + c5, cl)];
#pragma unroll
        for (int jj = 0; jj < 5; ++jj) {
            int e = __builtin_amdgcn_ds_bpermute(bpb + jj * 4, sj);
            e = (j0 + jj < cnt) ? e : n;           // invalid -> zero row
            half8v v = tS8r[(size_t)e * 5 + c5];
            if (jj & 1) a1 += v; else a0 += v;
        }
    }

    if (act) {
        float acc[8];
#pragma unroll
        for (int i = 0; i < 8; ++i) acc[i] = (float)a0[i] + (float)a1[i];

        half8v selfh = tS8r[(size_t)node * 5 + c5];
        float4 b0 = ((const float4*)bias)[c5 * 2];
        float4 b1 = ((const float4*)bias)[c5 * 2 + 1];
        float d = dinv[node];
        float4 o0, o1;
        o0.x = b0.x + d * (acc[0] + (float)selfh[0]);
        o0.y = b0.y + d * (acc[1] + (float)selfh[1]);
        o0.z = b0.z + d * (acc[2] + (float)selfh[2]);
        o0.w = b0.w + d * (acc[3] + (float)selfh[3]);
        o1.x = b1.x + d * (acc[4] + (float)selfh[4]);
        o1.y = b1.y + d * (acc[5] + (float)selfh[5]);
        o1.z = b1.z + d * (acc[6] + (float)selfh[6]);
        o1.w = b1.w + d * (acc[7] + (float)selfh[7]);
        *(float4*)(out + (size_t)node * 40 + c5 * 8) = o0;
        *(float4*)(out + (size_t)node * 40 + c5 * 8 + 4) = o1;
    }
}

// ---------------- launch ----------------

extern "C" void kernel_launch(void* const* d_in, const int* in_sizes, int n_in,
                              void* d_out, int out_size, void* d_ws, size_t ws_size,
                              hipStream_t stream) {
    const float* x  = (const float*)d_in[0];
    const int*   ei = (const int*)d_in[1];
    const int*   src = ei;
    const int*   dst = ei + N_EDGES;
    const float* W1 = (const float*)d_in[2];
    const float* b1 = (const float*)d_in[3];
    const float* W2 = (const float*)d_in[4];
    const float* b2 = (const float*)d_in[5];
    const float* W3 = (const float*)d_in[6];
    const float* b3 = (const float*)d_in[7];
    float* out = (float*)d_out;

    const int N = N_NODES, E = N_EDGES;

    char* p = (char*)d_ws;
    int*   cursor   = (int*)p;              p += 256 * 4;
    int*   gbase    = (int*)p;              p += 256 * 4;
    int*   histx    = (int*)p;              p += 256 * 4;   // hist[64] + gcursor[64] + dbase[64]
    float* dinv     = (float*)p;            p += (size_t)N * 4;
    int*   row_ptr  = (int*)p;              p += (size_t)(N + 4) * 4;
    int*   perm     = (int*)p;              p += (size_t)N * 4;
    int*   bucketed = (int*)p;              p += (size_t)NBUCK * BCAP * 4;
    int*   csr_src  = (int*)p;              p += (size_t)(E + 64) * 4;   // +64 slack for clamped reads
    p = (char*)(((size_t)p + 15) & ~(size_t)15);
    _Float16* Wt1   = (_Float16*)p;         p += (size_t)64 * 128 * 2;
    _Float16* Wt2   = (_Float16*)p;         p += (size_t)64 * 64 * 2;
    _Float16* bufA  = (_Float16*)p;         p += (size_t)(N + 64) * 64 * 2;  // fp16 tS (+zero row)
    p = (char*)(((size_t)p + 15) & ~(size_t)15);
    _Float16* bufB  = (_Float16*)p;         p += (size_t)N * 64 * 2;  // fp16 h

    int* hist    = histx;
    int* gcursor = histx + 64;
    int* dbase   = histx + 128;

    // ---- counting-sort CSR build + degree sort + W pre-transpose ----
    zero_small<<<1, 256, 0, stream>>>(cursor, NBUCK);
    zero_small<<<1, 256, 0, stream>>>(histx, 128);   // hist + gcursor
    transpose_w<128><<<32, 256, 0, stream>>>(W1, Wt1);
    transpose_w<64><<<16, 256, 0, stream>>>(W2, Wt2);
    multisplit<<<NCHUNK, 256, 0, stream>>>(src, dst, cursor, bucketed, E);
    bucket_scan<<<1, 256, 0, stream>>>(cursor, gbase);
    build_csr<<<NBUCK, 512, 0, stream>>>(bucketed, gbase, row_ptr, dinv, csr_src, hist, N);
    hist_scan<<<1, 64, 0, stream>>>(hist, dbase);
    perm_scatter<<<(N + 255) / 256, 256, 0, stream>>>(row_ptr, dbase, gcursor, perm, N);

    const int agg64Grid = N / 32;            // 3125, exact
    const int agg40Grid = (N + 47) / 48;     // 2084
    const int gemmGrid = (N + 63) / 64;

    // layer 1: x fp32 -> tS fp16 (MFMA); aggregate+relu -> h fp16
    gemm_mfma64<128, float><<<gemmGrid, 256, 0, stream>>>(x, Wt1, dinv, bufA, N);
    aggregate64g<true><<<agg64Grid, 256, 0, stream>>>(bufA, row_ptr, csr_src, perm, dinv, b1, bufB, N);

    // layer 2: h fp16 -> tS fp16 (MFMA); aggregate+relu -> h fp16
    gemm_mfma64<64, _Float16><<<gemmGrid, 256, 0, stream>>>(bufB, Wt2, dinv, bufA, N);
    aggregate64g<true><<<agg64Grid, 256, 0, stream>>>(bufA, row_ptr, csr_src, perm, dinv, b2, bufB, N);

    // layer 3: h fp16 -> tS40 fp16 (VALU); aggregate -> out fp32
    gemm_rt<64, 40, _Float16><<<gemmGrid, 256, 0, stream>>>(bufB, W3, dinv, bufA, N);
    aggregate40p<<<agg40Grid, 256, 0, stream>>>(bufA, row_ptr, csr_src, perm, dinv, b3, out, N);
}